// Round 2
// baseline (857.713 us; speedup 1.0000x reference)
//
#include <hip/hip_runtime.h>
#include <hip/hip_bf16.h>

// CLIPCrossProductClassifier on MI355X.
// h[b,n] = sum_k A[b,k] * W1[k,n],  A[b, i*512+j] = imgn[b,i]*txtn[b,j]
// M=512, N=512, K=262144. W1 (512 MB f32) is read exactly once:
// each WG covers all of M, one 64-wide N slice, and a split-K chunk
// (grid = 8 N-tiles x 32 splits = 256 WGs = 1/CU).
//
// Pipeline: W1 f32 -> regs (4-buffer ring, issue t+3 / LDS-write t+1: 2-step
// lead ~1300cy > 900cy HBM latency) -> bf16 cvt -> LDS (3-slot ring) ->
// ds_read_b128 B-frags. A-frags built in-register: bf16(img[b,i]*txt[b,j]).
// Barrier = raw s_barrier + lgkmcnt(0) ONLY (T4: counted vmcnt stays in
// flight across barriers; __syncthreads would drain vmcnt(0) and serialize
// HBM latency into every step).

typedef float f4 __attribute__((ext_vector_type(4)));
typedef short bf8v __attribute__((ext_vector_type(8)));
typedef unsigned short u16;
typedef unsigned int u32;

#define DD 512
#define NT 8        // N tiles of 64
#define BN 64
#define SPLITK 32
#define ISTR 16     // i-rows per split
#define NJW 16      // j-windows of 32
#define NSTEP 256   // NJW * ISTR
#define W1LD 40     // padded k-stride (elems): 80B rows -> b128 reads 2-way (free)
#define TXLD 40

__device__ __forceinline__ u16 f2bf(float f) {
  __hip_bfloat16 h = __float2bfloat16(f);
  union { __hip_bfloat16 h; u16 u; } c; c.h = h; return c.u;
}
__device__ __forceinline__ float lo_bf(u32 d) { return __uint_as_float(d << 16); }
__device__ __forceinline__ float hi_bf(u32 d) { return __uint_as_float(d & 0xffff0000u); }

// ---------------- kernel 1: L2-normalize rows, cast bf16 -------------------
// img -> imgn_t transposed [i][b]; txt -> txtn [b][j]
__global__ __launch_bounds__(256) void ccpc_norm(
    const float* __restrict__ img, const float* __restrict__ txt,
    u16* __restrict__ imgn_t, u16* __restrict__ txtn) {
  int b = blockIdx.x & 511;
  bool is_txt = blockIdx.x >= 512;
  const float* src = (is_txt ? txt : img) + (size_t)b * DD;
  int t = threadIdx.x;
  float x0 = src[t], x1 = src[t + 256];
  float ss = x0 * x0 + x1 * x1;
  #pragma unroll
  for (int o = 32; o > 0; o >>= 1) ss += __shfl_down(ss, o);
  __shared__ float wsum[4];
  if ((t & 63) == 0) wsum[t >> 6] = ss;
  __syncthreads();
  float tot = wsum[0] + wsum[1] + wsum[2] + wsum[3];
  float sc = 1.0f / fmaxf(sqrtf(tot), 1e-12f);
  u16 u0 = f2bf(x0 * sc), u1 = f2bf(x1 * sc);
  if (!is_txt) {
    imgn_t[(size_t)t * DD + b] = u0;
    imgn_t[(size_t)(t + 256) * DD + b] = u1;
  } else {
    txtn[(size_t)b * DD + t] = u0;
    txtn[(size_t)b * DD + t + 256] = u1;
  }
}

// ---------------- kernel 2: split-K implicit-A GEMM ------------------------
__global__ __launch_bounds__(512, 2) void ccpc_gemm(
    const float* __restrict__ W1, const u16* __restrict__ imgn_t,
    const u16* __restrict__ txtn, float* __restrict__ part) {
  __shared__ u16 lds_w1[3 * 64 * W1LD];   // 3-deep ring of [n=64][k=40] tiles
  __shared__ u16 lds_tx[512 * TXLD];      // txt tile [b=512][j-window=40]

  const int tid = threadIdx.x;
  const int bid = blockIdx.x;
  const int nt = bid & (NT - 1), sp = bid >> 3;
  const int n0 = nt * BN;
  const int i0 = sp * ISTR;
  const int wv = tid >> 6, l = tid & 63, l15 = l & 15, l4 = l >> 4;

  const int scol = tid & 63;         // W1 tile col (n)
  const int srow = (tid >> 6) * 4;   // W1 tile k-row base (4 rows per thread)
  const int gcol = n0 + scol;

  f4 acc[4][4];
  #pragma unroll
  for (int a = 0; a < 4; ++a)
    #pragma unroll
    for (int c = 0; c < 4; ++c) acc[a][c] = {0.f, 0.f, 0.f, 0.f};

  float buf0[4], buf1[4], buf2[4], buf3[4];
  int4 treg0, treg1, treg2, treg3;
  u32 tpk[4][4];   // packed bf16 txt frags, reused over 16 i-steps

  auto issueW1 = [&](int t, float (&ld)[4]) {
    int rb = (i0 + (t & (ISTR - 1))) * DD + (t >> 4) * 32 + srow;
    const float* p = W1 + (size_t)rb * DD + gcol;
    ld[0] = p[0]; ld[1] = p[DD]; ld[2] = p[2 * DD]; ld[3] = p[3 * DD];
  };
  auto writeW1 = [&](int t, float (&ld)[4]) {
    u32 d0 = ((u32)f2bf(ld[1]) << 16) | f2bf(ld[0]);
    u32 d1 = ((u32)f2bf(ld[3]) << 16) | f2bf(ld[2]);
    u16* dst = lds_w1 + (t % 3) * (64 * W1LD) + scol * W1LD + srow;
    *reinterpret_cast<uint2*>(dst) = make_uint2(d0, d1);
  };
  auto issueTX = [&](int jw) {
    const int4* p = reinterpret_cast<const int4*>(txtn + (size_t)tid * DD + jw * 32);
    treg0 = p[0]; treg1 = p[1]; treg2 = p[2]; treg3 = p[3];
  };
  auto writeTX = [&]() {
    int4* dst = reinterpret_cast<int4*>(lds_tx + (size_t)tid * TXLD);
    dst[0] = treg0; dst[1] = treg1; dst[2] = treg2; dst[3] = treg3;
  };
  auto readTX = [&]() {
    #pragma unroll
    for (int m = 0; m < 4; ++m) {
      const uint4* p = reinterpret_cast<const uint4*>(
          lds_tx + (wv * 64 + m * 16 + l15) * TXLD + l4 * 8);
      uint4 v = *p;
      tpk[m][0] = v.x; tpk[m][1] = v.y; tpk[m][2] = v.z; tpk[m][3] = v.w;
    }
  };

  auto compute = [&](int t) {
    const int i = t & (ISTR - 1);
    // B frags from LDS ring (b128, 2-way banked = free)
    bf8v bfr[4];
    const u16* wb = lds_w1 + (t % 3) * (64 * W1LD);
    #pragma unroll
    for (int fn = 0; fn < 4; ++fn) {
      const uint4* p = reinterpret_cast<const uint4*>(wb + (fn * 16 + l15) * W1LD + l4 * 8);
      uint4 v = *p;
      union { u32 u[4]; bf8v v8; } cb;
      cb.u[0] = v.x; cb.u[1] = v.y; cb.u[2] = v.z; cb.u[3] = v.w;
      bfr[fn] = cb.v8;
    }
    // img scalars (16 KB slice per WG -> L1-hot after first window)
    const int irow = (i0 + i) * DD + wv * 64 + l15;
    float im[4];
    im[0] = __uint_as_float(((u32)imgn_t[irow]) << 16);
    im[1] = __uint_as_float(((u32)imgn_t[irow + 16]) << 16);
    im[2] = __uint_as_float(((u32)imgn_t[irow + 32]) << 16);
    im[3] = __uint_as_float(((u32)imgn_t[irow + 48]) << 16);
    // A frags on the fly + 16 MFMA
    #pragma unroll
    for (int m = 0; m < 4; ++m) {
      union { u32 u[4]; bf8v v8; } ca;
      #pragma unroll
      for (int d = 0; d < 4; ++d) {
        float p0 = lo_bf(tpk[m][d]) * im[m];
        float p1 = hi_bf(tpk[m][d]) * im[m];
        ca.u[d] = ((u32)f2bf(p1) << 16) | f2bf(p0);
      }
      #pragma unroll
      for (int fn = 0; fn < 4; ++fn)
        acc[m][fn] = __builtin_amdgcn_mfma_f32_16x16x32_bf16(ca.v8, bfr[fn], acc[m][fn], 0, 0, 0);
    }
  };

  // barrier that does NOT drain vmcnt: LDS visibility only.
  auto stepBar = [&]() {
    asm volatile("s_waitcnt lgkmcnt(0)" ::: "memory");
    __builtin_amdgcn_s_barrier();
  };

  auto body = [&](int t, float (&ldI)[4], float (&ldC)[4]) {
    if ((t & (ISTR - 1)) == 0) readTX();                         // new j-window frags
    if (t + 3 < NSTEP) issueW1(t + 3, ldI);                      // depth-3 prefetch
    if ((t & (ISTR - 1)) == 4 && (t >> 4) + 1 < NJW) issueTX((t >> 4) + 1);
    compute(t);
    if (t + 1 < NSTEP) writeW1(t + 1, ldC);
    if ((t & (ISTR - 1)) == (ISTR - 1) && t + 1 < NSTEP) writeTX();
    stepBar();
  };

  // prologue: tiles 0,1,2 in flight; tile0 + txt jw0 staged
  issueW1(0, buf0);
  issueW1(1, buf1);
  issueW1(2, buf2);
  issueTX(0);
  writeW1(0, buf0);
  writeTX();
  stepBar();

  for (int t = 0; t < NSTEP; t += 4) {
    body(t + 0, buf3, buf1);   // issue t+3 -> buf[(t+3)&3], write t+1 from buf[(t+1)&3]
    body(t + 1, buf0, buf2);
    body(t + 2, buf1, buf3);
    body(t + 3, buf2, buf0);
  }

  // epilogue: store partials. C layout: col = l&15, row = (l>>4)*4 + r
  float* pout = part + (size_t)sp * (512 * 512);
  #pragma unroll
  for (int m = 0; m < 4; ++m) {
    #pragma unroll
    for (int fn = 0; fn < 4; ++fn) {
      int brow = wv * 64 + m * 16 + l4 * 4;
      int hcol = n0 + fn * 16 + l15;
      #pragma unroll
      for (int r = 0; r < 4; ++r)
        pout[(size_t)(brow + r) * 512 + hcol] = acc[m][fn][r];
    }
  }
}

// ---------------- kernel 3: reduce splits + bias + relu + W2 GEMV ----------
__global__ __launch_bounds__(512) void ccpc_fin(
    const float* __restrict__ part, const float* __restrict__ b1,
    const float* __restrict__ w2, const float* __restrict__ b2,
    float* __restrict__ out) {
  int b = blockIdx.x, h = threadIdx.x;
  const float* p = part + (size_t)b * 512 + h;
  float s = 0.f;
  #pragma unroll
  for (int sp = 0; sp < SPLITK; ++sp) s += p[(size_t)sp * (512 * 512)];
  float hv = fmaxf(s + b1[h], 0.f) * w2[h];
  #pragma unroll
  for (int o = 32; o > 0; o >>= 1) hv += __shfl_down(hv, o);
  __shared__ float red[8];
  if ((h & 63) == 0) red[h >> 6] = hv;
  __syncthreads();
  if (h == 0) {
    float r = 0.f;
    #pragma unroll
    for (int w = 0; w < 8; ++w) r += red[w];
    out[b] = r + b2[0];
  }
}

extern "C" void kernel_launch(void* const* d_in, const int* in_sizes, int n_in,
                              void* d_out, int out_size, void* d_ws, size_t ws_size,
                              hipStream_t stream) {
  const float* img = (const float*)d_in[0];
  const float* txt = (const float*)d_in[1];
  const float* W1  = (const float*)d_in[2];
  const float* b1  = (const float*)d_in[3];
  const float* W2  = (const float*)d_in[4];
  const float* b2  = (const float*)d_in[5];
  float* out = (float*)d_out;

  char* ws = (char*)d_ws;
  u16* imgn_t = (u16*)ws;                    // 512*512*2 = 524288 B
  u16* txtn   = (u16*)(ws + 524288);         // 524288 B
  float* part = (float*)(ws + 1048576);      // 32 MB (32 x 512 x 512 f32)

  ccpc_norm<<<1024, 256, 0, stream>>>(img, txt, imgn_t, txtn);
  ccpc_gemm<<<256, 512, 0, stream>>>(W1, imgn_t, txtn, part);
  ccpc_fin<<<512, 512, 0, stream>>>(part, b1, W2, b2, out);
}